// Round 16
// baseline (2716.918 us; speedup 1.0000x reference)
//
#include <hip/hip_runtime.h>
#include <hip/hip_bf16.h>
#include <math.h>

#define VSZ 50257
#define VPAD2 50432         // VSZ padded to multiple of 256
#define NLAYER 12
#define NH 12
#define EMB 768
#define TSEQ 1024
#define NB 4
#define MROWS (NB * TSEQ)   // 4096
#define DHEAD 64
#define LN_EPS 1e-5f

typedef __attribute__((ext_vector_type(8))) short bf16x8;
typedef __attribute__((ext_vector_type(4))) float f32x4;

__device__ __forceinline__ void load_lds16(const void* g, void* l) {
    __builtin_amdgcn_global_load_lds((const __attribute__((address_space(1))) unsigned int*)g,
                                     (__attribute__((address_space(3))) unsigned int*)l,
                                     16, 0, 0);
}

// ---------------- fused embed + wte-convert ----------------
__global__ void embed_wte_kernel(const int* __restrict__ idx, const float* __restrict__ wte,
                                 const float* __restrict__ wpe, float* __restrict__ x,
                                 __hip_bfloat16* __restrict__ wteB) {
    int bid = blockIdx.x;
    int tid = threadIdx.x;          // 0..191, 4 floats each = 768
    if (bid < MROWS) {
        int t = bid & (TSEQ - 1);
        int tok = idx[bid];
        float4 a = *(const float4*)&wte[(size_t)tok * EMB + tid * 4];
        float4 p = *(const float4*)&wpe[(size_t)t * EMB + tid * 4];
        a.x += p.x; a.y += p.y; a.z += p.z; a.w += p.w;
        *(float4*)&x[(size_t)bid * EMB + tid * 4] = a;
    } else {
        int row = bid - MROWS;
        union { short4 s4; __hip_bfloat16 h[4]; } u;
        if (row < VSZ) {
            float4 a = *(const float4*)&wte[(size_t)row * EMB + tid * 4];
            u.h[0] = __float2bfloat16(a.x); u.h[1] = __float2bfloat16(a.y);
            u.h[2] = __float2bfloat16(a.z); u.h[3] = __float2bfloat16(a.w);
        } else {
            u.h[0] = u.h[1] = u.h[2] = u.h[3] = __float2bfloat16(0.0f);
        }
        *(short4*)&wteB[(size_t)row * EMB + tid * 4] = u.s4;
    }
}

// ---------------- layernorm body (256 threads, row = blockIdx) ----------------
template <bool ACC>
__device__ __forceinline__ void ln_body(float* __restrict__ x, const float* __restrict__ p0,
                                        const float* __restrict__ p1,
                                        const float* __restrict__ g, const float* __restrict__ b,
                                        __hip_bfloat16* __restrict__ out, int row,
                                        float* __restrict__ smem) {
    float* xr = x + (size_t)row * EMB;
    __hip_bfloat16* yr = out + (size_t)row * EMB;
    int tid = threadIdx.x;
    float v0, v1, v2;
    if (ACC) {
        const float* q0 = p0 + (size_t)row * EMB;
        const float* q1 = p1 + (size_t)row * EMB;
        v0 = xr[tid]       + q0[tid]       + q1[tid];
        v1 = xr[tid + 256] + q0[tid + 256] + q1[tid + 256];
        v2 = xr[tid + 512] + q0[tid + 512] + q1[tid + 512];
        xr[tid] = v0; xr[tid + 256] = v1; xr[tid + 512] = v2;
    } else {
        v0 = xr[tid]; v1 = xr[tid + 256]; v2 = xr[tid + 512];
    }
    float s = v0 + v1 + v2;
    float ss = v0 * v0 + v1 * v1 + v2 * v2;
    #pragma unroll
    for (int i = 1; i < 64; i <<= 1) {
        s  += __shfl_xor(s, i, 64);
        ss += __shfl_xor(ss, i, 64);
    }
    float* sm = smem;
    float* sv = smem + 4;
    int lane = tid & 63, wid = tid >> 6;
    if (lane == 0) { sm[wid] = s; sv[wid] = ss; }
    __syncthreads();
    float sum = sm[0] + sm[1] + sm[2] + sm[3];
    float sqs = sv[0] + sv[1] + sv[2] + sv[3];
    float mean = sum * (1.0f / EMB);
    float var = sqs * (1.0f / EMB) - mean * mean;
    float rstd = rsqrtf(var + LN_EPS);
    yr[tid]       = __float2bfloat16((v0 - mean) * rstd * g[tid]       + b[tid]);
    yr[tid + 256] = __float2bfloat16((v1 - mean) * rstd * g[tid + 256] + b[tid + 256]);
    yr[tid + 512] = __float2bfloat16((v2 - mean) * rstd * g[tid + 512] + b[tid + 512]);
}

// ---------------- standalone ln_acc (used for ln2 and lnf) ----------------
__global__ void ln_acc_kernel(float* __restrict__ x, const float* __restrict__ p0,
                              const float* __restrict__ p1,
                              const float* __restrict__ g, const float* __restrict__ b,
                              __hip_bfloat16* __restrict__ out) {
    __shared__ float smem[8];
    ln_body<true>(x, p0, p1, g, b, out, blockIdx.x, smem);
}

// ---------------- fused per-layer ln(+acc) + 4-matrix weight transpose ----------------
template <bool ACC>
__global__ void ln_convT4_kernel(float* __restrict__ x, const float* __restrict__ p0,
                                 const float* __restrict__ p1,
                                 const float* __restrict__ lg, const float* __restrict__ lb,
                                 __hip_bfloat16* __restrict__ out,
                                 const float* __restrict__ aw, const float* __restrict__ pw,
                                 const float* __restrict__ fw, const float* __restrict__ mw,
                                 __hip_bfloat16* __restrict__ awT, __hip_bfloat16* __restrict__ pwT,
                                 __hip_bfloat16* __restrict__ fwT, __hip_bfloat16* __restrict__ mwT) {
    __shared__ float tile[32][33];
    int bid = blockIdx.x;
    if (bid < MROWS) {
        ln_body<ACC>(x, p0, p1, lg, lb, out, bid, &tile[0][0]);
        return;
    }
    int cbid = bid - MROWS;
    const float* W; __hip_bfloat16* Wt; int K, N, t;
    if (cbid < 1728)      { W = aw; Wt = awT; K = 768;  N = 2304; t = cbid; }
    else if (cbid < 2304) { W = pw; Wt = pwT; K = 768;  N = 768;  t = cbid - 1728; }
    else if (cbid < 4608) { W = fw; Wt = fwT; K = 768;  N = 3072; t = cbid - 2304; }
    else                  { W = mw; Wt = mwT; K = 3072; N = 768;  t = cbid - 4608; }
    int NT = N >> 5;
    int n0 = (t % NT) << 5, k0 = (t / NT) << 5;
    int tid = threadIdx.x;
    int i = tid >> 3, q = tid & 7;
    float4 v = *(const float4*)&W[(size_t)(k0 + i) * N + n0 + q * 4];
    tile[i][q * 4 + 0] = v.x; tile[i][q * 4 + 1] = v.y;
    tile[i][q * 4 + 2] = v.z; tile[i][q * 4 + 3] = v.w;
    __syncthreads();
    union { short4 s4; __hip_bfloat16 h[4]; } u;
    u.h[0] = __float2bfloat16(tile[q * 4 + 0][i]);
    u.h[1] = __float2bfloat16(tile[q * 4 + 1][i]);
    u.h[2] = __float2bfloat16(tile[q * 4 + 2][i]);
    u.h[3] = __float2bfloat16(tile[q * 4 + 3][i]);
    *(short4*)&Wt[(size_t)(n0 + i) * K + k0 + q * 4] = u.s4;
}

// ---------------- 128x128 bf16 MFMA GEMM, 2-phase double-buffered (T3 minimum) ----------------
// 512 threads = 8 waves (2 wr x 4 wc); per-wave out 64x32 (acc[4][2]); BK=64.
// Per K-step: STAGE(kt+1 -> buf p^1) BEFORE ds_read(buf p)+MFMA; one vmcnt(0)+barrier
// per tile at step end (drain semantics -> tail guard safe). LDS 64 KB -> 2 blocks/CU.
// Conflict-free [128][64] rows (128 B, 8-granule XOR both-sides swizzle, rule #21).
// SPLITK: chunk = low bit of swizzled wg; chunk0 -> Cf (+bias), chunk1 -> Cp1.
// OUT: 0=fp32, 1=bf16 Cb, 2=qkv-split (cols<1536 -> Cb, else vT transposed)
template <bool GELU, bool RES, int OUT, bool SPLITK>
__global__ __launch_bounds__(512) void gemm_bt(
                        const __hip_bfloat16* __restrict__ A, const __hip_bfloat16* __restrict__ B,
                        const float* __restrict__ bias, const float* __restrict__ res,
                        float* __restrict__ Cf, __hip_bfloat16* __restrict__ Cb,
                        __hip_bfloat16* __restrict__ vt, float* __restrict__ Cp1,
                        int Kc, int lda, int ldc, int Nclip) {
    __shared__ __hip_bfloat16 Ash[2][128 * 64];
    __shared__ __hip_bfloat16 Bsh[2][128 * 64];
    const int tid = threadIdx.x;
    const int lane = tid & 63, wid = tid >> 6;
    const int wr = wid >> 2, wc = wid & 3;

    const int nwg_all = gridDim.x;
    const int cpx = nwg_all >> 3;
    int wg = (blockIdx.x & 7) * cpx + (blockIdx.x >> 3);
    int chunk = 0, nwg = nwg_all;
    if (SPLITK) { chunk = wg & 1; wg >>= 1; nwg = nwg_all >> 1; }
    const int NT = nwg >> 5;
    const int bandsz = NT << 3;
    const int band = wg / bandsz;
    const int rem = wg - band * bandsz;
    const int m0 = (band * 8 + (rem & 7)) * 128;
    const int n0 = (rem >> 3) * 128;
    const int koff = SPLITK ? chunk * Kc : 0;

    f32x4 acc[4][2] = {};
    const int srow = lane >> 3;
    const int scol = ((lane & 7) ^ srow) * 8;

    const int lr16 = lane & 15;
    const int hi = lane >> 4;
    const int nt = Kc >> 6;

    // stage K-tile KT into buffer BUF (4 gload_lds x 8 waves = full 128x64 A + B)
    #define GB_STG(KT, BUF) do { \
        _Pragma("unroll") \
        for (int it_ = 0; it_ < 2; ++it_) { \
            int c_ = wid + it_ * 8; \
            load_lds16(A + (size_t)(m0 + c_ * 8 + srow) * lda + koff + (KT) * 64 + scol, \
                       &Ash[BUF][c_ * 512]); \
            load_lds16(B + (size_t)(n0 + c_ * 8 + srow) * lda + koff + (KT) * 64 + scol, \
                       &Bsh[BUF][c_ * 512]); \
        } \
    } while (0)

    GB_STG(0, 0);
    asm volatile("s_waitcnt vmcnt(0)" ::: "memory");
    __builtin_amdgcn_s_barrier();

    int p = 0;
    for (int kt = 0; kt < nt; ++kt) {
        if (kt + 1 < nt) GB_STG(kt + 1, p ^ 1);   // issue next-tile loads FIRST
        bf16x8 a[4][2], b[2][2];
        #pragma unroll
        for (int m = 0; m < 4; ++m)
            #pragma unroll
            for (int kk = 0; kk < 2; ++kk) {
                int ra = wr * 64 + m * 16 + lr16;
                int ca = (kk * 32 + hi * 8) ^ ((ra & 7) * 8);
                a[m][kk] = *(const bf16x8*)&Ash[p][ra * 64 + ca];
            }
        #pragma unroll
        for (int n = 0; n < 2; ++n)
            #pragma unroll
            for (int kk = 0; kk < 2; ++kk) {
                int rb = wc * 32 + n * 16 + lr16;
                int cb = (kk * 32 + hi * 8) ^ ((rb & 7) * 8);
                b[n][kk] = *(const bf16x8*)&Bsh[p][rb * 64 + cb];
            }
        asm volatile("s_waitcnt lgkmcnt(0)" ::: "memory");
        __builtin_amdgcn_sched_barrier(0);
        __builtin_amdgcn_s_setprio(1);
        #pragma unroll
        for (int kk = 0; kk < 2; ++kk)
            #pragma unroll
            for (int m = 0; m < 4; ++m)
                #pragma unroll
                for (int n = 0; n < 2; ++n)
                    acc[m][n] = __builtin_amdgcn_mfma_f32_16x16x32_bf16(a[m][kk], b[n][kk], acc[m][n], 0, 0, 0);
        __builtin_amdgcn_s_setprio(0);
        asm volatile("s_waitcnt vmcnt(0)" ::: "memory");   // next tile landed (drain: tail-safe)
        __builtin_amdgcn_s_barrier();                       // all waves' ds_reads of p done
        p ^= 1;
    }
    #undef GB_STG

    float* Co = (SPLITK && chunk) ? Cp1 : Cf;
    const bool dobias = bias && (!SPLITK || chunk == 0);
    const int crow0 = m0 + wr * 64, ccol0 = n0 + wc * 32;
    #pragma unroll
    for (int m = 0; m < 4; ++m) {
        #pragma unroll
        for (int n = 0; n < 2; ++n) {
            int col = ccol0 + n * 16 + lr16;
            if (col >= Nclip) continue;
            float bv = dobias ? bias[col] : 0.0f;
            #pragma unroll
            for (int j = 0; j < 4; ++j) {
                int r = crow0 + m * 16 + hi * 4 + j;
                float v = acc[m][n][j] + bv;
                if (GELU) {
                    float t = 0.7978845608028654f * (v + 0.044715f * v * v * v);
                    v = 0.5f * v * (1.0f + tanhf(t));
                }
                if (RES) v += res[(size_t)r * ldc + col];
                if (OUT == 0) Co[(size_t)r * ldc + col] = v;
                else if (OUT == 1) Cb[(size_t)r * ldc + col] = __float2bfloat16(v);
                else {
                    if (col < 2 * EMB) Cb[(size_t)r * (2 * EMB) + col] = __float2bfloat16(v);
                    else {
                        int hh = (col - 2 * EMB) >> 6, dd = (col - 2 * EMB) & 63;
                        int bb = r >> 10, tt = r & 1023;
                        vt[(((size_t)bb * NH + hh) * 64 + dd) * TSEQ + tt] = __float2bfloat16(v);
                    }
                }
            }
        }
    }
}

// ---------------- 256x256 8-phase GEMM for lm_head (round-8, verified) ----------------
#define G256_STAGE_A(KT, MH, P) do { \
    int ktw_ = (KT) % 12; \
    load_lds16(A + (size_t)(m0 + (MH) * 64 + srow) * 768 + ktw_ * 64 + sgr8, \
               &lds[(P) * 2][(MH) * 8192 + wid * 512]); \
    load_lds16(A + (size_t)(m0 + 128 + (MH) * 64 + srow) * 768 + ktw_ * 64 + sgr8, \
               &lds[(P) * 2][(MH) * 8192 + 4096 + wid * 512]); \
} while (0)

#define G256_STAGE_B(KT, NH, P) do { \
    int ktw_ = (KT) % 12; \
    load_lds16(Bm + (size_t)(bwc0 * 64 + (NH) * 32 + brow) * 768 + ktw_ * 64 + sgr8, \
               &lds[(P) * 2 + 1][(NH) * 8192 + wid * 512]); \
    load_lds16(Bm + (size_t)((2 + bwc0) * 64 + (NH) * 32 + brow) * 768 + ktw_ * 64 + sgr8, \
               &lds[(P) * 2 + 1][(NH) * 8192 + 4096 + wid * 512]); \
} while (0)

#define G256_PHASE(MH, NH, P, STAGE_STMT, VM) do { \
    bf16x8 af[4][2], bf[2][2]; \
    _Pragma("unroll") \
    for (int f = 0; f < 4; ++f) \
        _Pragma("unroll") \
        for (int kk = 0; kk < 2; ++kk) { \
            int pr = (MH) * 128 + wr * 64 + f * 16 + lr16; \
            af[f][kk] = *(const bf16x8*)((const char*)lds[(P) * 2] + pr * 128 + ((kk * 64 + hi * 16) ^ ((lr16 & 7) << 4))); \
        } \
    _Pragma("unroll") \
    for (int nn = 0; nn < 2; ++nn) \
        _Pragma("unroll") \
        for (int kk = 0; kk < 2; ++kk) { \
            int pr = (NH) * 128 + wc * 32 + nn * 16 + lr16; \
            bf[nn][kk] = *(const bf16x8*)((const char*)lds[(P) * 2 + 1] + pr * 128 + ((kk * 64 + hi * 16) ^ ((lr16 & 7) << 4))); \
        } \
    STAGE_STMT; \
    asm volatile("s_waitcnt vmcnt(" #VM ")" ::: "memory"); \
    __builtin_amdgcn_s_barrier(); \
    asm volatile("s_waitcnt lgkmcnt(0)" ::: "memory"); \
    __builtin_amdgcn_sched_barrier(0); \
    __builtin_amdgcn_s_setprio(1); \
    _Pragma("unroll") \
    for (int kk = 0; kk < 2; ++kk) \
        _Pragma("unroll") \
        for (int f = 0; f < 4; ++f) \
            _Pragma("unroll") \
            for (int nn = 0; nn < 2; ++nn) \
                acc[(MH) * 4 + f][(NH) * 2 + nn] = __builtin_amdgcn_mfma_f32_16x16x32_bf16( \
                    af[f][kk], bf[nn][kk], acc[(MH) * 4 + f][(NH) * 2 + nn], 0, 0, 0); \
    __builtin_amdgcn_s_setprio(0); \
    __builtin_amdgcn_s_barrier(); \
} while (0)

__global__ __launch_bounds__(512, 1) void gemm256(const __hip_bfloat16* __restrict__ A,
                                                  const __hip_bfloat16* __restrict__ Bw,
                                                  float* __restrict__ C) {
    __shared__ __hip_bfloat16 lds[4][16384];
    const int tid = threadIdx.x;
    const int lane = tid & 63, wid = tid >> 6;
    const int wr = wid >> 2, wc = wid & 3;
    const int lr16 = lane & 15, hi = lane >> 4;

    const int bid = blockIdx.x;
    const int wg = (bid & 7) * 394 + (bid >> 3);
    const int band = wg / 1576, rem = wg % 1576;
    const int mt = band * 8 + (rem & 7), nt = rem >> 3;
    const size_t m0 = (size_t)mt * 256;
    const __hip_bfloat16* Bm = Bw + (size_t)nt * 256 * 768;

    const int srow = tid >> 3;
    const int sgr8 = ((tid & 7) ^ ((tid >> 3) & 7)) * 8;
    const int brow = (tid >> 3) & 31;
    const int bwc0 = tid >> 8;

    f32x4 acc[8][4] = {};

    G256_STAGE_A(0, 0, 0);
    G256_STAGE_B(0, 0, 0);
    G256_STAGE_A(0, 1, 0);
    G256_STAGE_B(0, 1, 0);
    G256_STAGE_A(1, 0, 1);
    G256_STAGE_B(1, 0, 1);
    asm volatile("s_waitcnt vmcnt(8)" ::: "memory");
    __builtin_amdgcn_s_barrier();

    for (int kt2 = 0; kt2 < 12; kt2 += 2) {
        G256_PHASE(0, 0, 0, G256_STAGE_A(kt2 + 1, 1, 1), 6);
        G256_PHASE(0, 1, 0, G256_STAGE_B(kt2 + 1, 1, 1), 10);
        G256_PHASE(1, 0, 0, G256_STAGE_A(kt2 + 2, 0, 0), 10);
        G256_PHASE(1, 1, 0, G256_STAGE_B(kt2 + 2, 0, 0), 8);
        G256_PHASE(0, 0, 1, G256_STAGE_A(kt2 + 2, 1, 0), 6);
        G256_PHASE(0, 1, 1, G256_STAGE_B(kt2 + 2, 1, 0), 10);
        G256_PHASE(1, 0, 1, G256_STAGE_A(kt2 + 3, 0, 1), 10);
        G256_PHASE(1, 1, 1, G256_STAGE_B(kt2 + 3, 0, 1), 8);
    }

    const int ccol0 = nt * 256 + wc * 64;
    #pragma unroll
    for (int mf = 0; mf < 8; ++mf) {
        size_t row = m0 + wr * 128 + (mf >> 2) * 64 + (mf & 3) * 16 + hi * 4;
        #pragma unroll
        for (int nf = 0; nf < 4; ++nf) {
            int col = ccol0 + nf * 16 + lr16;
            if (col < VSZ) {
                #pragma unroll
                for (int j = 0; j < 4; ++j)
                    C[(row + j) * VSZ + col] = acc[mf][nf][j];
            }
        }
    }
}

// ---------------- MFMA flash attention (LDS-staged, fixed-shift softmax) ----------------
__global__ __launch_bounds__(256) void flash_attn(const __hip_bfloat16* __restrict__ qk,
                                                  const __hip_bfloat16* __restrict__ vT,
                                                  __hip_bfloat16* __restrict__ y) {
    const int qt = blockIdx.x, h = blockIdx.y, b = blockIdx.z;
    const int tid = threadIdx.x;
    const int lane = tid & 63, w = tid >> 6;
    const int g = lane >> 4, lr = lane & 15;

    __shared__ char KshB[64 * 128];
    __shared__ char VshB[64 * 128];
    __shared__ char PshB[4][16 * 128];

    const __hip_bfloat16* qrow = qk + ((size_t)(b * TSEQ + qt * 64 + w * 16 + lr)) * 1536 + h * 64;
    bf16x8 qf0 = *(const bf16x8*)(qrow + g * 8);
    bf16x8 qf1 = *(const bf16x8*)(qrow + 32 + g * 8);

    float l[4] = {0.f, 0.f, 0.f, 0.f};
    f32x4 o[4];
    #pragma unroll
    for (int n = 0; n < 4; ++n) o[n] = (f32x4){0.f, 0.f, 0.f, 0.f};

    const int r0 = tid >> 3;
    const int c0 = (tid & 7) * 8;

    for (int kt = 0; kt <= qt; ++kt) {
        __syncthreads();
        #pragma unroll
        for (int it = 0; it < 2; ++it) {
            int r = r0 + it * 32;
            bf16x8 kv = *(const bf16x8*)(qk + ((size_t)(b * TSEQ + kt * 64 + r)) * 1536 + EMB + h * 64 + c0);
            *(bf16x8*)(KshB + ((r * 128 + c0 * 2) ^ ((r & 7) << 4))) = kv;
            bf16x8 vv = *(const bf16x8*)(vT + (((size_t)(b * NH + h)) * 64 + r) * TSEQ + kt * 64 + c0);
            *(bf16x8*)(VshB + ((r * 128 + c0 * 2) ^ ((r & 7) << 4))) = vv;
        }
        __syncthreads();

        f32x4 s[4] = {};
        #pragma unroll
        for (int n = 0; n < 4; ++n) {
            int kr = n * 16 + lr;
            bf16x8 kb0 = *(const bf16x8*)(KshB + ((kr * 128 + g * 16) ^ ((kr & 7) << 4)));
            bf16x8 kb1 = *(const bf16x8*)(KshB + ((kr * 128 + 64 + g * 16) ^ ((kr & 7) << 4)));
            s[n] = __builtin_amdgcn_mfma_f32_16x16x32_bf16(qf0, kb0, s[n], 0, 0, 0);
            s[n] = __builtin_amdgcn_mfma_f32_16x16x32_bf16(qf1, kb1, s[n], 0, 0, 0);
        }

        const bool diag = (kt == qt);
        float pexp[4][4];
        #pragma unroll
        for (int n = 0; n < 4; ++n)
            #pragma unroll
            for (int j = 0; j < 4; ++j) {
                float v = s[n][j] * 0.125f;
                if (diag && (n * 16 + lr > w * 16 + g * 4 + j)) v = -1e30f;
                float p = __expf(v - 4.0f);
                pexp[n][j] = p;
                l[j] += p;
            }

        char* P = PshB[w];
        #pragma unroll
        for (int n = 0; n < 4; ++n)
            #pragma unroll
            for (int j = 0; j < 4; ++j) {
                int rw = g * 4 + j;
                *(__hip_bfloat16*)(P + ((rw * 128 + (n * 16 + lr) * 2) ^ ((rw & 7) << 4))) =
                    __float2bfloat16(pexp[n][j]);
            }
        asm volatile("s_waitcnt lgkmcnt(0)" ::: "memory");
        bf16x8 pa0 = *(const bf16x8*)(P + ((lr * 128 + g * 16) ^ ((lr & 7) << 4)));
        bf16x8 pa1 = *(const bf16x8*)(P + ((lr * 128 + 64 + g * 16) ^ ((lr & 7) << 4)));
        #pragma unroll
        for (int n = 0; n < 4; ++n) {
            int vr = n * 16 + lr;
            bf16x8 vb0 = *(const bf16x8*)(VshB + ((vr * 128 + g * 16) ^ ((vr & 7) << 4)));
            bf16x8 vb1 = *(const bf16x8*)(VshB + ((vr * 128 + 64 + g * 16) ^ ((vr & 7) << 4)));
            o[n] = __builtin_amdgcn_mfma_f32_16x16x32_bf16(pa0, vb0, o[n], 0, 0, 0);
            o[n] = __builtin_amdgcn_mfma_f32_16x16x32_bf16(pa1, vb1, o[n], 0, 0, 0);
        }
    }

    #pragma unroll
    for (int j = 0; j < 4; ++j)
        #pragma unroll
        for (int i = 1; i < 16; i <<= 1)
            l[j] += __shfl_xor(l[j], i, 64);

    #pragma unroll
    for (int j = 0; j < 4; ++j) {
        float inv = 1.0f / l[j];
        int row = b * TSEQ + qt * 64 + w * 16 + g * 4 + j;
        #pragma unroll
        for (int n = 0; n < 4; ++n)
            y[(size_t)row * EMB + h * 64 + n * 16 + lr] = __float2bfloat16(o[n][j] * inv);
    }
}

// ---------------- launcher ----------------
extern "C" void kernel_launch(void* const* d_in, const int* in_sizes, int n_in,
                              void* d_out, int out_size, void* d_ws, size_t ws_size,
                              hipStream_t stream) {
    const int*   idx     = (const int*)d_in[0];
    const float* wte     = (const float*)d_in[1];
    const float* wpe     = (const float*)d_in[2];
    const float* ln1_g   = (const float*)d_in[3];
    const float* ln1_b   = (const float*)d_in[4];
    const float* attn_w  = (const float*)d_in[5];
    const float* attn_b  = (const float*)d_in[6];
    const float* proj_w  = (const float*)d_in[7];
    const float* proj_b  = (const float*)d_in[8];
    const float* ln2_g   = (const float*)d_in[9];
    const float* ln2_b   = (const float*)d_in[10];
    const float* fc_w    = (const float*)d_in[11];
    const float* fc_b    = (const float*)d_in[12];
    const float* mproj_w = (const float*)d_in[13];
    const float* mproj_b = (const float*)d_in[14];
    const float* lnf_g   = (const float*)d_in[15];
    const float* lnf_b   = (const float*)d_in[16];
    float* out = (float*)d_out;

    char* w = (char*)d_ws;
    float* x = (float*)w;                      w += (size_t)MROWS * EMB * 4;
    float* p0 = (float*)w;                     w += (size_t)MROWS * EMB * 4;
    float* p1 = (float*)w;                     w += (size_t)MROWS * EMB * 4;
    __hip_bfloat16* qkb = (__hip_bfloat16*)w;  w += (size_t)MROWS * 2 * EMB * 2;
    __hip_bfloat16* vTb = (__hip_bfloat16*)w;  w += (size_t)NB * NH * 64 * TSEQ * 2;
    __hip_bfloat16* h = (__hip_bfloat16*)w;    w += (size_t)MROWS * EMB * 2;
    __hip_bfloat16* y = (__hip_bfloat16*)w;    w += (size_t)MROWS * EMB * 2;
    __hip_bfloat16* g = (__hip_bfloat16*)w;    w += (size_t)MROWS * 4 * EMB * 2;
    __hip_bfloat16* wqkvT = (__hip_bfloat16*)w;   w += (size_t)3 * EMB * EMB * 2;
    __hip_bfloat16* wprojT = (__hip_bfloat16*)w;  w += (size_t)EMB * EMB * 2;
    __hip_bfloat16* wfcT = (__hip_bfloat16*)w;    w += (size_t)4 * EMB * EMB * 2;
    __hip_bfloat16* wmprojT = (__hip_bfloat16*)w; w += (size_t)4 * EMB * EMB * 2;
    __hip_bfloat16* wteB = (__hip_bfloat16*)w;    w += (size_t)VPAD2 * EMB * 2;

    dim3 blk192(192), blk256(256), blk512(512);

    embed_wte_kernel<<<MROWS + VPAD2, blk192, 0, stream>>>(idx, wte, wpe, x, wteB);

    for (int l = 0; l < NLAYER; l++) {
        const float* aw = attn_w + (size_t)l * EMB * 3 * EMB;
        const float* ab = attn_b + (size_t)l * 3 * EMB;
        const float* pw = proj_w + (size_t)l * EMB * EMB;
        const float* pb = proj_b + (size_t)l * EMB;
        const float* fw = fc_w   + (size_t)l * EMB * 4 * EMB;
        const float* fb = fc_b   + (size_t)l * 4 * EMB;
        const float* mw = mproj_w + (size_t)l * 4 * EMB * EMB;
        const float* mb = mproj_b + (size_t)l * EMB;

        if (l == 0)
            ln_convT4_kernel<false><<<MROWS + 6912, blk256, 0, stream>>>(
                x, nullptr, nullptr, ln1_g + l * EMB, ln1_b + l * EMB, h,
                aw, pw, fw, mw, wqkvT, wprojT, wfcT, wmprojT);
        else
            ln_convT4_kernel<true><<<MROWS + 6912, blk256, 0, stream>>>(
                x, p0, p1, ln1_g + l * EMB, ln1_b + l * EMB, h,
                aw, pw, fw, mw, wqkvT, wprojT, wfcT, wmprojT);

        gemm_bt<false, false, 2, false><<<dim3((3 * EMB / 128) * 32), blk512, 0, stream>>>(
            h, wqkvT, ab, nullptr, nullptr, qkb, vTb, nullptr, EMB, EMB, 3 * EMB, 3 * EMB);

        flash_attn<<<dim3(TSEQ / 64, NH, NB), blk256, 0, stream>>>(qkb, vTb, y);

        gemm_bt<false, false, 0, true><<<dim3((EMB / 128) * 32 * 2), blk512, 0, stream>>>(
            y, wprojT, pb, nullptr, p0, nullptr, nullptr, p1, EMB / 2, EMB, EMB, EMB);

        ln_acc_kernel<<<MROWS, blk256, 0, stream>>>(x, p0, p1, ln2_g + l * EMB, ln2_b + l * EMB, h);

        gemm_bt<true, false, 1, false><<<dim3((4 * EMB / 128) * 32), blk512, 0, stream>>>(
            h, wfcT, fb, nullptr, nullptr, g, nullptr, nullptr, EMB, EMB, 4 * EMB, 4 * EMB);

        gemm_bt<false, false, 0, true><<<dim3((EMB / 128) * 32 * 2), blk512, 0, stream>>>(
            g, wmprojT, mb, nullptr, p0, nullptr, nullptr, p1, 2 * EMB, 4 * EMB, EMB, EMB);
    }

    ln_acc_kernel<<<MROWS, blk256, 0, stream>>>(x, p0, p1, lnf_g, lnf_b, h);

    gemm256<<<dim3((VPAD2 / 256) * (MROWS / 256)), dim3(512), 0, stream>>>(h, wteB, out);
}

// Round 17
// 2512.416 us; speedup vs baseline: 1.0814x; 1.0814x over previous
//
#include <hip/hip_runtime.h>
#include <hip/hip_bf16.h>
#include <math.h>

#define VSZ 50257
#define VPAD2 50432         // VSZ padded to multiple of 256
#define NLAYER 12
#define NH 12
#define EMB 768
#define TSEQ 1024
#define NB 4
#define MROWS (NB * TSEQ)   // 4096
#define DHEAD 64
#define LN_EPS 1e-5f

typedef __attribute__((ext_vector_type(8))) short bf16x8;
typedef __attribute__((ext_vector_type(4))) float f32x4;

__device__ __forceinline__ void load_lds16(const void* g, void* l) {
    __builtin_amdgcn_global_load_lds((const __attribute__((address_space(1))) unsigned int*)g,
                                     (__attribute__((address_space(3))) unsigned int*)l,
                                     16, 0, 0);
}

// ---------------- fused embed + wte-convert ----------------
__global__ void embed_wte_kernel(const int* __restrict__ idx, const float* __restrict__ wte,
                                 const float* __restrict__ wpe, float* __restrict__ x,
                                 __hip_bfloat16* __restrict__ wteB) {
    int bid = blockIdx.x;
    int tid = threadIdx.x;          // 0..191, 4 floats each = 768
    if (bid < MROWS) {
        int t = bid & (TSEQ - 1);
        int tok = idx[bid];
        float4 a = *(const float4*)&wte[(size_t)tok * EMB + tid * 4];
        float4 p = *(const float4*)&wpe[(size_t)t * EMB + tid * 4];
        a.x += p.x; a.y += p.y; a.z += p.z; a.w += p.w;
        *(float4*)&x[(size_t)bid * EMB + tid * 4] = a;
    } else {
        int row = bid - MROWS;
        union { short4 s4; __hip_bfloat16 h[4]; } u;
        if (row < VSZ) {
            float4 a = *(const float4*)&wte[(size_t)row * EMB + tid * 4];
            u.h[0] = __float2bfloat16(a.x); u.h[1] = __float2bfloat16(a.y);
            u.h[2] = __float2bfloat16(a.z); u.h[3] = __float2bfloat16(a.w);
        } else {
            u.h[0] = u.h[1] = u.h[2] = u.h[3] = __float2bfloat16(0.0f);
        }
        *(short4*)&wteB[(size_t)row * EMB + tid * 4] = u.s4;
    }
}

// ---------------- layernorm body (256 threads, row = blockIdx) ----------------
template <bool ACC>
__device__ __forceinline__ void ln_body(float* __restrict__ x, const float* __restrict__ p0,
                                        const float* __restrict__ p1,
                                        const float* __restrict__ g, const float* __restrict__ b,
                                        __hip_bfloat16* __restrict__ out, int row,
                                        float* __restrict__ smem) {
    float* xr = x + (size_t)row * EMB;
    __hip_bfloat16* yr = out + (size_t)row * EMB;
    int tid = threadIdx.x;
    float v0, v1, v2;
    if (ACC) {
        const float* q0 = p0 + (size_t)row * EMB;
        const float* q1 = p1 + (size_t)row * EMB;
        v0 = xr[tid]       + q0[tid]       + q1[tid];
        v1 = xr[tid + 256] + q0[tid + 256] + q1[tid + 256];
        v2 = xr[tid + 512] + q0[tid + 512] + q1[tid + 512];
        xr[tid] = v0; xr[tid + 256] = v1; xr[tid + 512] = v2;
    } else {
        v0 = xr[tid]; v1 = xr[tid + 256]; v2 = xr[tid + 512];
    }
    float s = v0 + v1 + v2;
    float ss = v0 * v0 + v1 * v1 + v2 * v2;
    #pragma unroll
    for (int i = 1; i < 64; i <<= 1) {
        s  += __shfl_xor(s, i, 64);
        ss += __shfl_xor(ss, i, 64);
    }
    float* sm = smem;
    float* sv = smem + 4;
    int lane = tid & 63, wid = tid >> 6;
    if (lane == 0) { sm[wid] = s; sv[wid] = ss; }
    __syncthreads();
    float sum = sm[0] + sm[1] + sm[2] + sm[3];
    float sqs = sv[0] + sv[1] + sv[2] + sv[3];
    float mean = sum * (1.0f / EMB);
    float var = sqs * (1.0f / EMB) - mean * mean;
    float rstd = rsqrtf(var + LN_EPS);
    yr[tid]       = __float2bfloat16((v0 - mean) * rstd * g[tid]       + b[tid]);
    yr[tid + 256] = __float2bfloat16((v1 - mean) * rstd * g[tid + 256] + b[tid + 256]);
    yr[tid + 512] = __float2bfloat16((v2 - mean) * rstd * g[tid + 512] + b[tid + 512]);
}

// ---------------- standalone ln_acc (used for ln2 and lnf) ----------------
__global__ void ln_acc_kernel(float* __restrict__ x, const float* __restrict__ p0,
                              const float* __restrict__ p1,
                              const float* __restrict__ g, const float* __restrict__ b,
                              __hip_bfloat16* __restrict__ out) {
    __shared__ float smem[8];
    ln_body<true>(x, p0, p1, g, b, out, blockIdx.x, smem);
}

// ---------------- fused per-layer ln(+acc) + 4-matrix weight transpose ----------------
template <bool ACC>
__global__ void ln_convT4_kernel(float* __restrict__ x, const float* __restrict__ p0,
                                 const float* __restrict__ p1,
                                 const float* __restrict__ lg, const float* __restrict__ lb,
                                 __hip_bfloat16* __restrict__ out,
                                 const float* __restrict__ aw, const float* __restrict__ pw,
                                 const float* __restrict__ fw, const float* __restrict__ mw,
                                 __hip_bfloat16* __restrict__ awT, __hip_bfloat16* __restrict__ pwT,
                                 __hip_bfloat16* __restrict__ fwT, __hip_bfloat16* __restrict__ mwT) {
    __shared__ float tile[32][33];
    int bid = blockIdx.x;
    if (bid < MROWS) {
        ln_body<ACC>(x, p0, p1, lg, lb, out, bid, &tile[0][0]);
        return;
    }
    int cbid = bid - MROWS;
    const float* W; __hip_bfloat16* Wt; int K, N, t;
    if (cbid < 1728)      { W = aw; Wt = awT; K = 768;  N = 2304; t = cbid; }
    else if (cbid < 2304) { W = pw; Wt = pwT; K = 768;  N = 768;  t = cbid - 1728; }
    else if (cbid < 4608) { W = fw; Wt = fwT; K = 768;  N = 3072; t = cbid - 2304; }
    else                  { W = mw; Wt = mwT; K = 3072; N = 768;  t = cbid - 4608; }
    int NT = N >> 5;
    int n0 = (t % NT) << 5, k0 = (t / NT) << 5;
    int tid = threadIdx.x;
    int i = tid >> 3, q = tid & 7;
    float4 v = *(const float4*)&W[(size_t)(k0 + i) * N + n0 + q * 4];
    tile[i][q * 4 + 0] = v.x; tile[i][q * 4 + 1] = v.y;
    tile[i][q * 4 + 2] = v.z; tile[i][q * 4 + 3] = v.w;
    __syncthreads();
    union { short4 s4; __hip_bfloat16 h[4]; } u;
    u.h[0] = __float2bfloat16(tile[q * 4 + 0][i]);
    u.h[1] = __float2bfloat16(tile[q * 4 + 1][i]);
    u.h[2] = __float2bfloat16(tile[q * 4 + 2][i]);
    u.h[3] = __float2bfloat16(tile[q * 4 + 3][i]);
    *(short4*)&Wt[(size_t)(n0 + i) * K + k0 + q * 4] = u.s4;
}

// ---------------- 128x128 bf16 MFMA GEMM (round-15 known-good, 8 waves) ----------------
// 512 threads = 8 waves (2 wr x 4 wc); per-wave out 64x32 (acc[4][2]).
// BK=64, band-blocked XCD order, both-sides XOR-granule swizzle (rule #21).
// Single-buffered 32 KB LDS -> 4 blocks/CU (occupancy beats deeper pipeline at K<=3072;
// verified by two failed dbuf attempts, rounds 10 & 16).
// SPLITK: chunk = low bit of swizzled wg; chunk0 -> Cf (+bias), chunk1 -> Cp1.
// OUT: 0=fp32, 1=bf16 Cb, 2=qkv-split (cols<1536 -> Cb, else vT transposed)
template <bool GELU, bool RES, int OUT, bool SPLITK>
__global__ __launch_bounds__(512) void gemm_bt(
                        const __hip_bfloat16* __restrict__ A, const __hip_bfloat16* __restrict__ B,
                        const float* __restrict__ bias, const float* __restrict__ res,
                        float* __restrict__ Cf, __hip_bfloat16* __restrict__ Cb,
                        __hip_bfloat16* __restrict__ vt, float* __restrict__ Cp1,
                        int Kc, int lda, int ldc, int Nclip) {
    __shared__ __hip_bfloat16 Ash[128 * 64];
    __shared__ __hip_bfloat16 Bsh[128 * 64];
    const int tid = threadIdx.x;
    const int lane = tid & 63, wid = tid >> 6;
    const int wr = wid >> 2, wc = wid & 3;

    const int nwg_all = gridDim.x;
    const int cpx = nwg_all >> 3;
    int wg = (blockIdx.x & 7) * cpx + (blockIdx.x >> 3);
    int chunk = 0, nwg = nwg_all;
    if (SPLITK) { chunk = wg & 1; wg >>= 1; nwg = nwg_all >> 1; }
    const int NT = nwg >> 5;
    const int bandsz = NT << 3;
    const int band = wg / bandsz;
    const int rem = wg - band * bandsz;
    const int m0 = (band * 8 + (rem & 7)) * 128;
    const int n0 = (rem >> 3) * 128;
    const int koff = SPLITK ? chunk * Kc : 0;

    f32x4 acc[4][2] = {};
    const int srow = lane >> 3;
    const int scol = ((lane & 7) ^ srow) * 8;

    const int lr16 = lane & 15;
    const int hi = lane >> 4;

    for (int k0 = 0; k0 < Kc; k0 += 64) {
        #pragma unroll
        for (int it = 0; it < 2; ++it) {
            int c = wid + it * 8;        // chunk 0..15, 8 rows each
            const __hip_bfloat16* ga = A + (size_t)(m0 + c * 8 + srow) * lda + koff + k0 + scol;
            load_lds16(ga, &Ash[c * 512]);
            const __hip_bfloat16* gb = B + (size_t)(n0 + c * 8 + srow) * lda + koff + k0 + scol;
            load_lds16(gb, &Bsh[c * 512]);
        }
        __syncthreads();
        bf16x8 a[4][2], b[2][2];
        #pragma unroll
        for (int m = 0; m < 4; ++m)
            #pragma unroll
            for (int kk = 0; kk < 2; ++kk) {
                int ra = wr * 64 + m * 16 + lr16;
                int ca = (kk * 32 + hi * 8) ^ ((ra & 7) * 8);
                a[m][kk] = *(const bf16x8*)&Ash[ra * 64 + ca];
            }
        #pragma unroll
        for (int n = 0; n < 2; ++n)
            #pragma unroll
            for (int kk = 0; kk < 2; ++kk) {
                int rb = wc * 32 + n * 16 + lr16;
                int cb = (kk * 32 + hi * 8) ^ ((rb & 7) * 8);
                b[n][kk] = *(const bf16x8*)&Bsh[rb * 64 + cb];
            }
        #pragma unroll
        for (int kk = 0; kk < 2; ++kk)
            #pragma unroll
            for (int m = 0; m < 4; ++m)
                #pragma unroll
                for (int n = 0; n < 2; ++n)
                    acc[m][n] = __builtin_amdgcn_mfma_f32_16x16x32_bf16(a[m][kk], b[n][kk], acc[m][n], 0, 0, 0);
        __syncthreads();
    }

    float* Co = (SPLITK && chunk) ? Cp1 : Cf;
    const bool dobias = bias && (!SPLITK || chunk == 0);
    const int crow0 = m0 + wr * 64, ccol0 = n0 + wc * 32;
    #pragma unroll
    for (int m = 0; m < 4; ++m) {
        #pragma unroll
        for (int n = 0; n < 2; ++n) {
            int col = ccol0 + n * 16 + lr16;
            if (col >= Nclip) continue;
            float bv = dobias ? bias[col] : 0.0f;
            #pragma unroll
            for (int j = 0; j < 4; ++j) {
                int r = crow0 + m * 16 + hi * 4 + j;
                float v = acc[m][n][j] + bv;
                if (GELU) {
                    float t = 0.7978845608028654f * (v + 0.044715f * v * v * v);
                    v = 0.5f * v * (1.0f + tanhf(t));
                }
                if (RES) v += res[(size_t)r * ldc + col];
                if (OUT == 0) Co[(size_t)r * ldc + col] = v;
                else if (OUT == 1) Cb[(size_t)r * ldc + col] = __float2bfloat16(v);
                else {
                    if (col < 2 * EMB) Cb[(size_t)r * (2 * EMB) + col] = __float2bfloat16(v);
                    else {
                        int hh = (col - 2 * EMB) >> 6, dd = (col - 2 * EMB) & 63;
                        int bb = r >> 10, tt = r & 1023;
                        vt[(((size_t)bb * NH + hh) * 64 + dd) * TSEQ + tt] = __float2bfloat16(v);
                    }
                }
            }
        }
    }
}

// ---------------- 256x256 8-phase GEMM for lm_head (round-8, verified) ----------------
#define G256_STAGE_A(KT, MH, P) do { \
    int ktw_ = (KT) % 12; \
    load_lds16(A + (size_t)(m0 + (MH) * 64 + srow) * 768 + ktw_ * 64 + sgr8, \
               &lds[(P) * 2][(MH) * 8192 + wid * 512]); \
    load_lds16(A + (size_t)(m0 + 128 + (MH) * 64 + srow) * 768 + ktw_ * 64 + sgr8, \
               &lds[(P) * 2][(MH) * 8192 + 4096 + wid * 512]); \
} while (0)

#define G256_STAGE_B(KT, NH, P) do { \
    int ktw_ = (KT) % 12; \
    load_lds16(Bm + (size_t)(bwc0 * 64 + (NH) * 32 + brow) * 768 + ktw_ * 64 + sgr8, \
               &lds[(P) * 2 + 1][(NH) * 8192 + wid * 512]); \
    load_lds16(Bm + (size_t)((2 + bwc0) * 64 + (NH) * 32 + brow) * 768 + ktw_ * 64 + sgr8, \
               &lds[(P) * 2 + 1][(NH) * 8192 + 4096 + wid * 512]); \
} while (0)

#define G256_PHASE(MH, NH, P, STAGE_STMT, VM) do { \
    bf16x8 af[4][2], bf[2][2]; \
    _Pragma("unroll") \
    for (int f = 0; f < 4; ++f) \
        _Pragma("unroll") \
        for (int kk = 0; kk < 2; ++kk) { \
            int pr = (MH) * 128 + wr * 64 + f * 16 + lr16; \
            af[f][kk] = *(const bf16x8*)((const char*)lds[(P) * 2] + pr * 128 + ((kk * 64 + hi * 16) ^ ((lr16 & 7) << 4))); \
        } \
    _Pragma("unroll") \
    for (int nn = 0; nn < 2; ++nn) \
        _Pragma("unroll") \
        for (int kk = 0; kk < 2; ++kk) { \
            int pr = (NH) * 128 + wc * 32 + nn * 16 + lr16; \
            bf[nn][kk] = *(const bf16x8*)((const char*)lds[(P) * 2 + 1] + pr * 128 + ((kk * 64 + hi * 16) ^ ((lr16 & 7) << 4))); \
        } \
    STAGE_STMT; \
    asm volatile("s_waitcnt vmcnt(" #VM ")" ::: "memory"); \
    __builtin_amdgcn_s_barrier(); \
    asm volatile("s_waitcnt lgkmcnt(0)" ::: "memory"); \
    __builtin_amdgcn_sched_barrier(0); \
    __builtin_amdgcn_s_setprio(1); \
    _Pragma("unroll") \
    for (int kk = 0; kk < 2; ++kk) \
        _Pragma("unroll") \
        for (int f = 0; f < 4; ++f) \
            _Pragma("unroll") \
            for (int nn = 0; nn < 2; ++nn) \
                acc[(MH) * 4 + f][(NH) * 2 + nn] = __builtin_amdgcn_mfma_f32_16x16x32_bf16( \
                    af[f][kk], bf[nn][kk], acc[(MH) * 4 + f][(NH) * 2 + nn], 0, 0, 0); \
    __builtin_amdgcn_s_setprio(0); \
    __builtin_amdgcn_s_barrier(); \
} while (0)

__global__ __launch_bounds__(512, 1) void gemm256(const __hip_bfloat16* __restrict__ A,
                                                  const __hip_bfloat16* __restrict__ Bw,
                                                  float* __restrict__ C) {
    __shared__ __hip_bfloat16 lds[4][16384];
    const int tid = threadIdx.x;
    const int lane = tid & 63, wid = tid >> 6;
    const int wr = wid >> 2, wc = wid & 3;
    const int lr16 = lane & 15, hi = lane >> 4;

    const int bid = blockIdx.x;
    const int wg = (bid & 7) * 394 + (bid >> 3);
    const int band = wg / 1576, rem = wg % 1576;
    const int mt = band * 8 + (rem & 7), nt = rem >> 3;
    const size_t m0 = (size_t)mt * 256;
    const __hip_bfloat16* Bm = Bw + (size_t)nt * 256 * 768;

    const int srow = tid >> 3;
    const int sgr8 = ((tid & 7) ^ ((tid >> 3) & 7)) * 8;
    const int brow = (tid >> 3) & 31;
    const int bwc0 = tid >> 8;

    f32x4 acc[8][4] = {};

    G256_STAGE_A(0, 0, 0);
    G256_STAGE_B(0, 0, 0);
    G256_STAGE_A(0, 1, 0);
    G256_STAGE_B(0, 1, 0);
    G256_STAGE_A(1, 0, 1);
    G256_STAGE_B(1, 0, 1);
    asm volatile("s_waitcnt vmcnt(8)" ::: "memory");
    __builtin_amdgcn_s_barrier();

    for (int kt2 = 0; kt2 < 12; kt2 += 2) {
        G256_PHASE(0, 0, 0, G256_STAGE_A(kt2 + 1, 1, 1), 6);
        G256_PHASE(0, 1, 0, G256_STAGE_B(kt2 + 1, 1, 1), 10);
        G256_PHASE(1, 0, 0, G256_STAGE_A(kt2 + 2, 0, 0), 10);
        G256_PHASE(1, 1, 0, G256_STAGE_B(kt2 + 2, 0, 0), 8);
        G256_PHASE(0, 0, 1, G256_STAGE_A(kt2 + 2, 1, 0), 6);
        G256_PHASE(0, 1, 1, G256_STAGE_B(kt2 + 2, 1, 0), 10);
        G256_PHASE(1, 0, 1, G256_STAGE_A(kt2 + 3, 0, 1), 10);
        G256_PHASE(1, 1, 1, G256_STAGE_B(kt2 + 3, 0, 1), 8);
    }

    const int ccol0 = nt * 256 + wc * 64;
    #pragma unroll
    for (int mf = 0; mf < 8; ++mf) {
        size_t row = m0 + wr * 128 + (mf >> 2) * 64 + (mf & 3) * 16 + hi * 4;
        #pragma unroll
        for (int nf = 0; nf < 4; ++nf) {
            int col = ccol0 + nf * 16 + lr16;
            if (col < VSZ) {
                #pragma unroll
                for (int j = 0; j < 4; ++j)
                    C[(row + j) * VSZ + col] = acc[mf][nf][j];
            }
        }
    }
}

// ---------------- MFMA flash attention (LDS-staged, fixed-shift softmax) ----------------
__global__ __launch_bounds__(256) void flash_attn(const __hip_bfloat16* __restrict__ qk,
                                                  const __hip_bfloat16* __restrict__ vT,
                                                  __hip_bfloat16* __restrict__ y) {
    const int qt = blockIdx.x, h = blockIdx.y, b = blockIdx.z;
    const int tid = threadIdx.x;
    const int lane = tid & 63, w = tid >> 6;
    const int g = lane >> 4, lr = lane & 15;

    __shared__ char KshB[64 * 128];
    __shared__ char VshB[64 * 128];
    __shared__ char PshB[4][16 * 128];

    const __hip_bfloat16* qrow = qk + ((size_t)(b * TSEQ + qt * 64 + w * 16 + lr)) * 1536 + h * 64;
    bf16x8 qf0 = *(const bf16x8*)(qrow + g * 8);
    bf16x8 qf1 = *(const bf16x8*)(qrow + 32 + g * 8);

    float l[4] = {0.f, 0.f, 0.f, 0.f};
    f32x4 o[4];
    #pragma unroll
    for (int n = 0; n < 4; ++n) o[n] = (f32x4){0.f, 0.f, 0.f, 0.f};

    const int r0 = tid >> 3;
    const int c0 = (tid & 7) * 8;

    for (int kt = 0; kt <= qt; ++kt) {
        __syncthreads();
        #pragma unroll
        for (int it = 0; it < 2; ++it) {
            int r = r0 + it * 32;
            bf16x8 kv = *(const bf16x8*)(qk + ((size_t)(b * TSEQ + kt * 64 + r)) * 1536 + EMB + h * 64 + c0);
            *(bf16x8*)(KshB + ((r * 128 + c0 * 2) ^ ((r & 7) << 4))) = kv;
            bf16x8 vv = *(const bf16x8*)(vT + (((size_t)(b * NH + h)) * 64 + r) * TSEQ + kt * 64 + c0);
            *(bf16x8*)(VshB + ((r * 128 + c0 * 2) ^ ((r & 7) << 4))) = vv;
        }
        __syncthreads();

        f32x4 s[4] = {};
        #pragma unroll
        for (int n = 0; n < 4; ++n) {
            int kr = n * 16 + lr;
            bf16x8 kb0 = *(const bf16x8*)(KshB + ((kr * 128 + g * 16) ^ ((kr & 7) << 4)));
            bf16x8 kb1 = *(const bf16x8*)(KshB + ((kr * 128 + 64 + g * 16) ^ ((kr & 7) << 4)));
            s[n] = __builtin_amdgcn_mfma_f32_16x16x32_bf16(qf0, kb0, s[n], 0, 0, 0);
            s[n] = __builtin_amdgcn_mfma_f32_16x16x32_bf16(qf1, kb1, s[n], 0, 0, 0);
        }

        const bool diag = (kt == qt);
        float pexp[4][4];
        #pragma unroll
        for (int n = 0; n < 4; ++n)
            #pragma unroll
            for (int j = 0; j < 4; ++j) {
                float v = s[n][j] * 0.125f;
                if (diag && (n * 16 + lr > w * 16 + g * 4 + j)) v = -1e30f;
                float p = __expf(v - 4.0f);
                pexp[n][j] = p;
                l[j] += p;
            }

        char* P = PshB[w];
        #pragma unroll
        for (int n = 0; n < 4; ++n)
            #pragma unroll
            for (int j = 0; j < 4; ++j) {
                int rw = g * 4 + j;
                *(__hip_bfloat16*)(P + ((rw * 128 + (n * 16 + lr) * 2) ^ ((rw & 7) << 4))) =
                    __float2bfloat16(pexp[n][j]);
            }
        asm volatile("s_waitcnt lgkmcnt(0)" ::: "memory");
        bf16x8 pa0 = *(const bf16x8*)(P + ((lr * 128 + g * 16) ^ ((lr & 7) << 4)));
        bf16x8 pa1 = *(const bf16x8*)(P + ((lr * 128 + 64 + g * 16) ^ ((lr & 7) << 4)));
        #pragma unroll
        for (int n = 0; n < 4; ++n) {
            int vr = n * 16 + lr;
            bf16x8 vb0 = *(const bf16x8*)(VshB + ((vr * 128 + g * 16) ^ ((vr & 7) << 4)));
            bf16x8 vb1 = *(const bf16x8*)(VshB + ((vr * 128 + 64 + g * 16) ^ ((vr & 7) << 4)));
            o[n] = __builtin_amdgcn_mfma_f32_16x16x32_bf16(pa0, vb0, o[n], 0, 0, 0);
            o[n] = __builtin_amdgcn_mfma_f32_16x16x32_bf16(pa1, vb1, o[n], 0, 0, 0);
        }
    }

    #pragma unroll
    for (int j = 0; j < 4; ++j)
        #pragma unroll
        for (int i = 1; i < 16; i <<= 1)
            l[j] += __shfl_xor(l[j], i, 64);

    #pragma unroll
    for (int j = 0; j < 4; ++j) {
        float inv = 1.0f / l[j];
        int row = b * TSEQ + qt * 64 + w * 16 + g * 4 + j;
        #pragma unroll
        for (int n = 0; n < 4; ++n)
            y[(size_t)row * EMB + h * 64 + n * 16 + lr] = __float2bfloat16(o[n][j] * inv);
    }
}

// ---------------- launcher ----------------
extern "C" void kernel_launch(void* const* d_in, const int* in_sizes, int n_in,
                              void* d_out, int out_size, void* d_ws, size_t ws_size,
                              hipStream_t stream) {
    const int*   idx     = (const int*)d_in[0];
    const float* wte     = (const float*)d_in[1];
    const float* wpe     = (const float*)d_in[2];
    const float* ln1_g   = (const float*)d_in[3];
    const float* ln1_b   = (const float*)d_in[4];
    const float* attn_w  = (const float*)d_in[5];
    const float* attn_b  = (const float*)d_in[6];
    const float* proj_w  = (const float*)d_in[7];
    const float* proj_b  = (const float*)d_in[8];
    const float* ln2_g   = (const float*)d_in[9];
    const float* ln2_b   = (const float*)d_in[10];
    const float* fc_w    = (const float*)d_in[11];
    const float* fc_b    = (const float*)d_in[12];
    const float* mproj_w = (const float*)d_in[13];
    const float* mproj_b = (const float*)d_in[14];
    const float* lnf_g   = (const float*)d_in[15];
    const float* lnf_b   = (const float*)d_in[16];
    float* out = (float*)d_out;

    char* w = (char*)d_ws;
    float* x = (float*)w;                      w += (size_t)MROWS * EMB * 4;
    float* p0 = (float*)w;                     w += (size_t)MROWS * EMB * 4;
    float* p1 = (float*)w;                     w += (size_t)MROWS * EMB * 4;
    __hip_bfloat16* qkb = (__hip_bfloat16*)w;  w += (size_t)MROWS * 2 * EMB * 2;
    __hip_bfloat16* vTb = (__hip_bfloat16*)w;  w += (size_t)NB * NH * 64 * TSEQ * 2;
    __hip_bfloat16* h = (__hip_bfloat16*)w;    w += (size_t)MROWS * EMB * 2;
    __hip_bfloat16* y = (__hip_bfloat16*)w;    w += (size_t)MROWS * EMB * 2;
    __hip_bfloat16* g = (__hip_bfloat16*)w;    w += (size_t)MROWS * 4 * EMB * 2;
    __hip_bfloat16* wqkvT = (__hip_bfloat16*)w;   w += (size_t)3 * EMB * EMB * 2;
    __hip_bfloat16* wprojT = (__hip_bfloat16*)w;  w += (size_t)EMB * EMB * 2;
    __hip_bfloat16* wfcT = (__hip_bfloat16*)w;    w += (size_t)4 * EMB * EMB * 2;
    __hip_bfloat16* wmprojT = (__hip_bfloat16*)w; w += (size_t)4 * EMB * EMB * 2;
    __hip_bfloat16* wteB = (__hip_bfloat16*)w;    w += (size_t)VPAD2 * EMB * 2;

    dim3 blk192(192), blk256(256), blk512(512);

    embed_wte_kernel<<<MROWS + VPAD2, blk192, 0, stream>>>(idx, wte, wpe, x, wteB);

    for (int l = 0; l < NLAYER; l++) {
        const float* aw = attn_w + (size_t)l * EMB * 3 * EMB;
        const float* ab = attn_b + (size_t)l * 3 * EMB;
        const float* pw = proj_w + (size_t)l * EMB * EMB;
        const float* pb = proj_b + (size_t)l * EMB;
        const float* fw = fc_w   + (size_t)l * EMB * 4 * EMB;
        const float* fb = fc_b   + (size_t)l * 4 * EMB;
        const float* mw = mproj_w + (size_t)l * 4 * EMB * EMB;
        const float* mb = mproj_b + (size_t)l * EMB;

        if (l == 0)
            ln_convT4_kernel<false><<<MROWS + 6912, blk256, 0, stream>>>(
                x, nullptr, nullptr, ln1_g + l * EMB, ln1_b + l * EMB, h,
                aw, pw, fw, mw, wqkvT, wprojT, wfcT, wmprojT);
        else
            ln_convT4_kernel<true><<<MROWS + 6912, blk256, 0, stream>>>(
                x, p0, p1, ln1_g + l * EMB, ln1_b + l * EMB, h,
                aw, pw, fw, mw, wqkvT, wprojT, wfcT, wmprojT);

        gemm_bt<false, false, 2, false><<<dim3((3 * EMB / 128) * 32), blk512, 0, stream>>>(
            h, wqkvT, ab, nullptr, nullptr, qkb, vTb, nullptr, EMB, EMB, 3 * EMB, 3 * EMB);

        flash_attn<<<dim3(TSEQ / 64, NH, NB), blk256, 0, stream>>>(qkb, vTb, y);

        gemm_bt<false, false, 0, true><<<dim3((EMB / 128) * 32 * 2), blk512, 0, stream>>>(
            y, wprojT, pb, nullptr, p0, nullptr, nullptr, p1, EMB / 2, EMB, EMB, EMB);

        ln_acc_kernel<<<MROWS, blk256, 0, stream>>>(x, p0, p1, ln2_g + l * EMB, ln2_b + l * EMB, h);

        gemm_bt<true, false, 1, false><<<dim3((4 * EMB / 128) * 32), blk512, 0, stream>>>(
            h, wfcT, fb, nullptr, nullptr, g, nullptr, nullptr, EMB, EMB, 4 * EMB, 4 * EMB);

        gemm_bt<false, false, 0, true><<<dim3((EMB / 128) * 32 * 2), blk512, 0, stream>>>(
            g, wmprojT, mb, nullptr, p0, nullptr, nullptr, p1, 2 * EMB, 4 * EMB, EMB, EMB);
    }

    ln_acc_kernel<<<MROWS, blk256, 0, stream>>>(x, p0, p1, lnf_g, lnf_b, h);

    gemm256<<<dim3((VPAD2 / 256) * (MROWS / 256)), dim3(512), 0, stream>>>(h, wteB, out);
}